// Round 10
// baseline (170.861 us; speedup 1.0000x reference)
//
#include <hip/hip_runtime.h>
#include <hip/hip_bf16.h>

// ---------------- problem constants ----------------
#define NG      19
#define HEIGHT  256
#define WIDTH   512
#define HW      (HEIGHT*WIDTH)        // 131072
#define BATCH   4
#define TH      16                    // tile rows
#define TW      64                    // tile cols
#define HALO_R  18
#define HALO_CU 34                    // u32 cols = 68 bf16 cols, origin tc0-2
#define CH_U32  (HALO_R*HALO_CU)      // 612
#define LDS_U32 (5*CH_U32)            // 3060 u32 = 12240 B per copy
#define ROWB    (HALO_CU*4)           // 136 B per row
#define CHB     (CH_U32*4)            // 2448 B per channel
#define WFRAG_SHORTS (NG*64*16)
#define BIAS_FLOATS  (NG*16)

typedef __attribute__((ext_vector_type(8))) short short8;
typedef __attribute__((ext_vector_type(4))) float f32x4;
typedef __attribute__((ext_vector_type(2))) float f32x2;
typedef __attribute__((ext_vector_type(4))) unsigned int u32x4;

static __device__ __forceinline__ unsigned int bfbits(float f) {
    return (unsigned int)__builtin_bit_cast(unsigned short, __float2bfloat16(f));
}
static __device__ __forceinline__ unsigned int pack2(float lo, float hi) {
    return bfbits(lo) | (bfbits(hi) << 16);
}

// K enumeration: k = m*4 + kc, m = (ic*3+kr) in 0..14, kc in 0..3.
// kc==3 and m==15 are zero-weight pad slots.
// A row = oc_perm = s*4 + gate -> D gives lane-local gates per (pixel,slab).
// exp2 scales folded: gates i,f,o scaled by -1.4427 (sigma(A)=1/(1+2^a)),
// gate g scaled by -2.8854 (tanh(A)=(1-2^a)/(1+2^a)).
__global__ void wxform_kernel(const float* __restrict__ W,
                              const float* __restrict__ b,
                              short* __restrict__ wdst,
                              float* __restrict__ bdst) {
    int i = blockIdx.x * 256 + threadIdx.x;
    if (i < WFRAG_SHORTS) {
        int g   = i / 1024;
        int r   = i & 1023;
        int l   = r >> 4;          // lane 0..63
        int j   = r & 15;          // element 0..15
        int q   = l >> 4;
        int row = l & 15;          // oc_perm = s*4 + gate
        int s    = row >> 2;
        int gate = row & 3;
        int half = j >> 3;
        int jj   = j & 7;
        int m  = 8*half + 2*q + (jj >> 2);   // (ic,kr) combo index
        int kc = jj & 3;
        float wv = 0.0f;
        if (m <= 14 && kc < 3) {
            int ic = m / 3, kr = m % 3;
            int oc = g*16 + gate*4 + s;
            float scale = (gate == 3) ? -2.88539008f : -1.44269504f;
            wv = scale * W[((oc*5 + ic)*3 + kr)*3 + kc];
        }
        wdst[i] = (short)__builtin_bit_cast(unsigned short, __float2bfloat16(wv));
    } else if (i < WFRAG_SHORTS + BIAS_FLOATS) {
        int idx = i - WFRAG_SHORTS;
        int g = idx >> 4;
        int r = idx & 15;
        int s = r >> 2, gate = r & 3;
        float scale = (gate == 3) ? -2.88539008f : -1.44269504f;
        bdst[idx] = scale * b[g*16 + gate*4 + s];   // [g][s][gate]
    }
}

// Dual-copy LDS: lds0[j] = bf16(halo cols 2j, 2j+1); lds1[j] = bf16(cols 2j+1, 2j+2)
// (halo col hc = global col tc0-2+hc). Every 4-tap window is then two 4B-aligned
// LDS dwords: n=1 -> lds0[d+1,d+2]; n=3 -> lds0[d+2,d+3]; n=0 -> lds1[d,d+1];
// n=2 -> lds1[d+1,d+2], with d = (combo byte base + 8*li + tr*ROWB)/4 (even).
__launch_bounds__(256, 4)
__global__ void convlstm_mfma(const float* __restrict__ x,
                              const float* __restrict__ h,
                              const float* __restrict__ c,
                              const short* __restrict__ wfrag,
                              const float* __restrict__ biasp,
                              float* __restrict__ out) {
    __shared__ unsigned int lds0[LDS_U32];
    __shared__ unsigned int lds1[LDS_U32];

    const int t     = threadIdx.x;
    const int bid   = blockIdx.x;
    const int plane = bid >> 7;            // (b*19+g)
    const int tile  = bid & 127;
    const int tr0   = (tile >> 3) * TH;
    const int tc0   = (tile & 7)  * TW;
    const int g     = plane % NG;

    const int w  = t >> 6;     // wave: tile rows w*4..w*4+3
    const int l  = t & 63;
    const int q  = l >> 4;     // slab
    const int li = l & 15;     // pixel tile-col = 4*li + n

    const int NC_OFF   = BATCH * NG * 4 * HW;   // 39,845,888
    const int rowbase0 = (plane*4 + q)*HW + (tr0 + w*4)*WIDTH + tc0 + 4*li;

    // all 4 c rows in flight immediately, PLAIN cached loads (through L2/L3)
    f32x4 cp[4];
    #pragma unroll
    for (int tr4 = 0; tr4 < 4; ++tr4)
        cp[tr4] = *reinterpret_cast<const f32x4*>(c + rowbase0 + tr4*WIDTH);

    // A fragments + bias (scales folded)
    const short8* ap = reinterpret_cast<const short8*>(wfrag + (g*64 + l)*16);
    const short8 a_lo = ap[0];
    const short8 a_hi = ap[1];
    const f32x4 bias4 = *reinterpret_cast<const f32x4*>(biasp + g*16 + q*4);

    // ---- staging: 12 slots/thread, incremental (ch,r,j2) walk, 2 batches ----
    const float* xb = x + plane * HW;
    const float* hb = h + (plane * 4) * HW;
    const bool lt = (tc0 == 0), rt = (tc0 == 448);

    int r  = t / HALO_CU;          // 0..7
    int j2 = t - r * HALO_CU;      // 0..33
    int ch = 0;

    #pragma unroll
    for (int half = 0; half < 2; ++half) {
        f32x2 pf[6]; float ex[6]; int pidx[6]; bool vld[6];
        #pragma unroll
        for (int k2 = 0; k2 < 6; ++k2) {
            const int k = half*6 + k2;
            const int p = t + 256*k;
            const bool v = (k < 11) ? true : (p < LDS_U32);
            pidx[k2] = p;  vld[k2] = v;
            const int  gr  = tr0 + r - 1;
            const bool rok = v && ((unsigned)gr < HEIGHT);
            const bool pok = rok && !(lt && j2 == 0) && !(rt && j2 == 33);
            const bool eok = rok && !(rt && j2 >= 32);
            const float* bp = (ch == 0) ? xb : (hb + (ch - 1) * HW);
            const int off = gr*WIDTH + tc0 + 2*j2 - 2;
            f32x2 z; z[0] = 0.0f; z[1] = 0.0f;
            pf[k2] = pok ? *reinterpret_cast<const f32x2*>(bp + off) : z;
            ex[k2] = eok ? bp[off + 2] : 0.0f;
            // advance by +256 slots: 256 = 7*34 + 18
            j2 += 18; r += 7;
            if (j2 >= HALO_CU) { j2 -= HALO_CU; r += 1; }
            if (r  >= HALO_R)  { r  -= HALO_R;  ch += 1; }
        }
        #pragma unroll
        for (int k2 = 0; k2 < 6; ++k2) {
            if (vld[k2]) {
                lds0[pidx[k2]] = pack2(pf[k2][0], pf[k2][1]);
                lds1[pidx[k2]] = pack2(pf[k2][1], ex[k2]);
            }
        }
    }

    asm volatile("s_waitcnt lgkmcnt(0)" ::: "memory");
    __builtin_amdgcn_s_barrier();
    asm volatile("" ::: "memory");

    // ---- per-lane combo dword bases (even -> all windows 4B/8B aligned) ----
    int dbase[4];
    #pragma unroll
    for (int i = 0; i < 4; ++i) {
        int m = (i < 2) ? (2*q + i) : (8 + 2*q + (i - 2));
        if (m > 14) m = 14;                      // m==15 pad: weight is 0
        dbase[i] = ((m/3)*CHB + (m%3)*ROWB + 8*li) >> 2;
    }

    #pragma unroll
    for (int tr4 = 0; tr4 < 4; ++tr4) {
        const int tr  = w*4 + tr4;
        const int drw = tr * (ROWB >> 2);
        const int d0 = dbase[0] + drw, d1 = dbase[1] + drw;
        const int d2 = dbase[2] + drw, d3 = dbase[3] + drw;

        float nh4[4], nc4[4];
        #pragma unroll
        for (int n = 0; n < 4; ++n) {
            // window quads loaded DIRECTLY from LDS (no VALU extraction)
            u32x4 blo_u, bhi_u;
            if (n == 0) {
                blo_u[0]=lds1[d0];   blo_u[1]=lds1[d0+1]; blo_u[2]=lds1[d1];   blo_u[3]=lds1[d1+1];
                bhi_u[0]=lds1[d2];   bhi_u[1]=lds1[d2+1]; bhi_u[2]=lds1[d3];   bhi_u[3]=lds1[d3+1];
            } else if (n == 1) {
                blo_u[0]=lds0[d0+1]; blo_u[1]=lds0[d0+2]; blo_u[2]=lds0[d1+1]; blo_u[3]=lds0[d1+2];
                bhi_u[0]=lds0[d2+1]; bhi_u[1]=lds0[d2+2]; bhi_u[2]=lds0[d3+1]; bhi_u[3]=lds0[d3+2];
            } else if (n == 2) {
                blo_u[0]=lds1[d0+1]; blo_u[1]=lds1[d0+2]; blo_u[2]=lds1[d1+1]; blo_u[3]=lds1[d1+2];
                bhi_u[0]=lds1[d2+1]; bhi_u[1]=lds1[d2+2]; bhi_u[2]=lds1[d3+1]; bhi_u[3]=lds1[d3+2];
            } else {
                blo_u[0]=lds0[d0+2]; blo_u[1]=lds0[d0+3]; blo_u[2]=lds0[d1+2]; blo_u[3]=lds0[d1+3];
                bhi_u[0]=lds0[d2+2]; bhi_u[1]=lds0[d2+3]; bhi_u[2]=lds0[d3+2]; bhi_u[3]=lds0[d3+3];
            }
            const short8 blo = __builtin_bit_cast(short8, blo_u);
            const short8 bhi = __builtin_bit_cast(short8, bhi_u);

            f32x4 acc = bias4;
            acc = __builtin_amdgcn_mfma_f32_16x16x32_bf16(a_lo, blo, acc, 0, 0, 0);
            acc = __builtin_amdgcn_mfma_f32_16x16x32_bf16(a_hi, bhi, acc, 0, 0, 0);

            // fused-reciprocal LSTM epilogue: 5 exp2 + 2 rcp per pixel
            const float cv = cp[tr4][n];
            const float u  = __builtin_amdgcn_exp2f(acc[0]);
            const float v  = __builtin_amdgcn_exp2f(acc[1]);
            const float wo = __builtin_amdgcn_exp2f(acc[2]);
            const float z  = __builtin_amdgcn_exp2f(acc[3]);
            const float pu = 1.0f + u,  pv = 1.0f + v;
            const float pw = 1.0f + wo, pz = 1.0f + z;
            const float puz = pu * pz;
            const float r1  = __builtin_amdgcn_rcpf(pv * puz);
            const float nc  = fmaf(cv, puz, (1.0f - z) * pv) * r1;
            const float tt2 = __builtin_amdgcn_exp2f(-2.88539008f * nc);
            const float r2  = __builtin_amdgcn_rcpf(pw * (1.0f + tt2));
            nc4[n] = nc;
            nh4[n] = (1.0f - tt2) * r2;
        }

        // dense 16B PLAIN stores (through L2, fill-proven 7 TB/s path)
        const int rowchan = rowbase0 + tr4*WIDTH;
        f32x4 nhv; nhv[0]=nh4[0]; nhv[1]=nh4[1]; nhv[2]=nh4[2]; nhv[3]=nh4[3];
        f32x4 ncv; ncv[0]=nc4[0]; ncv[1]=nc4[1]; ncv[2]=nc4[2]; ncv[3]=nc4[3];
        *reinterpret_cast<f32x4*>(out + rowchan)          = nhv;
        *reinterpret_cast<f32x4*>(out + NC_OFF + rowchan) = ncv;
    }
}

extern "C" void kernel_launch(void* const* d_in, const int* in_sizes, int n_in,
                              void* d_out, int out_size, void* d_ws, size_t ws_size,
                              hipStream_t stream) {
    (void)in_sizes; (void)n_in; (void)out_size; (void)ws_size;
    const float* x = (const float*)d_in[0];
    const float* h = (const float*)d_in[1];
    const float* c = (const float*)d_in[2];
    const float* W = (const float*)d_in[3];
    const float* b = (const float*)d_in[4];
    float* out = (float*)d_out;

    short* wdst = (short*)d_ws;                                         // 38,912 B
    float* bdst = (float*)((char*)d_ws + WFRAG_SHORTS * sizeof(short)); // +1,216 B

    hipLaunchKernelGGL(wxform_kernel,
                       dim3((WFRAG_SHORTS + BIAS_FLOATS + 255) / 256), dim3(256),
                       0, stream, W, b, wdst, bdst);
    hipLaunchKernelGGL(convlstm_mfma, dim3(BATCH * NG * 128), dim3(256),
                       0, stream, x, h, c, (const short*)wdst, bdst, out);
}

// Round 11
// 140.455 us; speedup vs baseline: 1.2165x; 1.2165x over previous
//
#include <hip/hip_runtime.h>
#include <hip/hip_bf16.h>

// ---------------- problem constants ----------------
#define NG      19
#define HEIGHT  256
#define WIDTH   512
#define HW      (HEIGHT*WIDTH)        // 131072
#define BATCH   4
#define TH      16                    // tile rows
#define TW      64                    // tile cols
#define HALO_R  18
#define HALO_CU 34                    // u32 cols = 68 bf16 cols, origin tc0-2
#define CH_U32  (HALO_R*HALO_CU)      // 612
#define LDS_U32 (5*CH_U32)            // 3060 u32 = 12240 B per copy
#define ROWB    (HALO_CU*4)           // 136 B per row
#define CHB     (CH_U32*4)            // 2448 B per channel
#define WFRAG_SHORTS (NG*64*16)
#define BIAS_FLOATS  (NG*16)

typedef __attribute__((ext_vector_type(8))) short short8;
typedef __attribute__((ext_vector_type(4))) float f32x4;
typedef __attribute__((ext_vector_type(2))) float f32x2;
typedef __attribute__((ext_vector_type(4))) unsigned int u32x4;

static __device__ __forceinline__ unsigned int bfbits(float f) {
    return (unsigned int)__builtin_bit_cast(unsigned short, __float2bfloat16(f));
}
static __device__ __forceinline__ unsigned int pack2(float lo, float hi) {
    return bfbits(lo) | (bfbits(hi) << 16);
}

// K enumeration: k = m*4 + kc, m = (ic*3+kr) in 0..14, kc in 0..3.
// kc==3 and m==15 are zero-weight pad slots.
// A row = oc_perm = s*4 + gate -> D gives lane-local gates per (pixel,slab).
// exp2 scales folded: gates i,f,o scaled by -1.4427 (sigma(A)=1/(1+2^a)),
// gate g scaled by -2.8854 (tanh(A)=(1-2^a)/(1+2^a)).
__global__ void wxform_kernel(const float* __restrict__ W,
                              const float* __restrict__ b,
                              short* __restrict__ wdst,
                              float* __restrict__ bdst) {
    int i = blockIdx.x * 256 + threadIdx.x;
    if (i < WFRAG_SHORTS) {
        int g   = i / 1024;
        int r   = i & 1023;
        int l   = r >> 4;          // lane 0..63
        int j   = r & 15;          // element 0..15
        int q   = l >> 4;
        int row = l & 15;          // oc_perm = s*4 + gate
        int s    = row >> 2;
        int gate = row & 3;
        int half = j >> 3;
        int jj   = j & 7;
        int m  = 8*half + 2*q + (jj >> 2);   // (ic,kr) combo index
        int kc = jj & 3;
        float wv = 0.0f;
        if (m <= 14 && kc < 3) {
            int ic = m / 3, kr = m % 3;
            int oc = g*16 + gate*4 + s;
            float scale = (gate == 3) ? -2.88539008f : -1.44269504f;
            wv = scale * W[((oc*5 + ic)*3 + kr)*3 + kc];
        }
        wdst[i] = (short)__builtin_bit_cast(unsigned short, __float2bfloat16(wv));
    } else if (i < WFRAG_SHORTS + BIAS_FLOATS) {
        int idx = i - WFRAG_SHORTS;
        int g = idx >> 4;
        int r = idx & 15;
        int s = r >> 2, gate = r & 3;
        float scale = (gate == 3) ? -2.88539008f : -1.44269504f;
        bdst[idx] = scale * b[g*16 + gate*4 + s];   // [g][s][gate]
    }
}

// Dual-copy LDS: lds0[j] = bf16(halo cols 2j, 2j+1); lds1[j] = bf16(cols 2j+1, 2j+2)
// (halo col hc = global col tc0-2+hc). Every 4-tap window is then two 4B-aligned
// LDS dwords: n=1 -> lds0[d+1,d+2]; n=3 -> lds0[d+2,d+3]; n=0 -> lds1[d,d+1];
// n=2 -> lds1[d+1,d+2], with d = (combo byte base + 8*li + tr*ROWB)/4 (even).
__launch_bounds__(256, 6)
__global__ void convlstm_mfma(const float* __restrict__ x,
                              const float* __restrict__ h,
                              const float* __restrict__ c,
                              const short* __restrict__ wfrag,
                              const float* __restrict__ biasp,
                              float* __restrict__ out) {
    __shared__ unsigned int lds0[LDS_U32];
    __shared__ unsigned int lds1[LDS_U32];

    const int t     = threadIdx.x;
    const int bid   = blockIdx.x;
    const int plane = bid >> 7;            // (b*19+g)
    const int tile  = bid & 127;
    const int tr0   = (tile >> 3) * TH;
    const int tc0   = (tile & 7)  * TW;
    const int g     = plane % NG;

    const int w  = t >> 6;     // wave: tile rows w*4..w*4+3
    const int l  = t & 63;
    const int q  = l >> 4;     // slab
    const int li = l & 15;     // pixel tile-col = 4*li + n

    const int NC_OFF   = BATCH * NG * 4 * HW;   // 39,845,888
    const int rowbase0 = (plane*4 + q)*HW + (tr0 + w*4)*WIDTH + tc0 + 4*li;

    // all 4 c rows in flight immediately (nontemporal: read-once stream)
    f32x4 cp[4];
    #pragma unroll
    for (int tr4 = 0; tr4 < 4; ++tr4)
        cp[tr4] = __builtin_nontemporal_load(
            reinterpret_cast<const f32x4*>(c + rowbase0 + tr4*WIDTH));

    // A fragments + bias (scales folded)
    const short8* ap = reinterpret_cast<const short8*>(wfrag + (g*64 + l)*16);
    const short8 a_lo = ap[0];
    const short8 a_hi = ap[1];
    const f32x4 bias4 = *reinterpret_cast<const f32x4*>(biasp + g*16 + q*4);

    // ---- staging: 12 slots/thread, incremental (ch,r,j2) walk, 2 batches ----
    const float* xb = x + plane * HW;
    const float* hb = h + (plane * 4) * HW;
    const bool lt = (tc0 == 0), rt = (tc0 == 448);

    int r  = t / HALO_CU;          // 0..7
    int j2 = t - r * HALO_CU;      // 0..33
    int ch = 0;

    #pragma unroll
    for (int half = 0; half < 2; ++half) {
        f32x2 pf[6]; float ex[6]; int pidx[6]; bool vld[6];
        #pragma unroll
        for (int k2 = 0; k2 < 6; ++k2) {
            const int k = half*6 + k2;
            const int p = t + 256*k;
            const bool v = (k < 11) ? true : (p < LDS_U32);
            pidx[k2] = p;  vld[k2] = v;
            const int  gr  = tr0 + r - 1;
            const bool rok = v && ((unsigned)gr < HEIGHT);
            const bool pok = rok && !(lt && j2 == 0) && !(rt && j2 == 33);
            const bool eok = rok && !(rt && j2 >= 32);
            const float* bp = (ch == 0) ? xb : (hb + (ch - 1) * HW);
            const int off = gr*WIDTH + tc0 + 2*j2 - 2;
            f32x2 z; z[0] = 0.0f; z[1] = 0.0f;
            pf[k2] = pok ? *reinterpret_cast<const f32x2*>(bp + off) : z;
            ex[k2] = eok ? bp[off + 2] : 0.0f;
            // advance by +256 slots: 256 = 7*34 + 18
            j2 += 18; r += 7;
            if (j2 >= HALO_CU) { j2 -= HALO_CU; r += 1; }
            if (r  >= HALO_R)  { r  -= HALO_R;  ch += 1; }
        }
        #pragma unroll
        for (int k2 = 0; k2 < 6; ++k2) {
            if (vld[k2]) {
                lds0[pidx[k2]] = pack2(pf[k2][0], pf[k2][1]);
                lds1[pidx[k2]] = pack2(pf[k2][1], ex[k2]);
            }
        }
    }

    asm volatile("s_waitcnt lgkmcnt(0)" ::: "memory");
    __builtin_amdgcn_s_barrier();
    asm volatile("" ::: "memory");

    // ---- per-lane combo dword bases (even -> all windows 4B/8B aligned) ----
    int dbase[4];
    #pragma unroll
    for (int i = 0; i < 4; ++i) {
        int m = (i < 2) ? (2*q + i) : (8 + 2*q + (i - 2));
        if (m > 14) m = 14;                      // m==15 pad: weight is 0
        dbase[i] = ((m/3)*CHB + (m%3)*ROWB + 8*li) >> 2;
    }

    #pragma unroll
    for (int tr4 = 0; tr4 < 4; ++tr4) {
        const int tr  = w*4 + tr4;
        const int drw = tr * (ROWB >> 2);
        const int d0 = dbase[0] + drw, d1 = dbase[1] + drw;
        const int d2 = dbase[2] + drw, d3 = dbase[3] + drw;

        float nh4[4], nc4[4];
        #pragma unroll
        for (int n = 0; n < 4; ++n) {
            // window quads loaded DIRECTLY from LDS (no VALU extraction)
            u32x4 blo_u, bhi_u;
            if (n == 0) {
                blo_u[0]=lds1[d0];   blo_u[1]=lds1[d0+1]; blo_u[2]=lds1[d1];   blo_u[3]=lds1[d1+1];
                bhi_u[0]=lds1[d2];   bhi_u[1]=lds1[d2+1]; bhi_u[2]=lds1[d3];   bhi_u[3]=lds1[d3+1];
            } else if (n == 1) {
                blo_u[0]=lds0[d0+1]; blo_u[1]=lds0[d0+2]; blo_u[2]=lds0[d1+1]; blo_u[3]=lds0[d1+2];
                bhi_u[0]=lds0[d2+1]; bhi_u[1]=lds0[d2+2]; bhi_u[2]=lds0[d3+1]; bhi_u[3]=lds0[d3+2];
            } else if (n == 2) {
                blo_u[0]=lds1[d0+1]; blo_u[1]=lds1[d0+2]; blo_u[2]=lds1[d1+1]; blo_u[3]=lds1[d1+2];
                bhi_u[0]=lds1[d2+1]; bhi_u[1]=lds1[d2+2]; bhi_u[2]=lds1[d3+1]; bhi_u[3]=lds1[d3+2];
            } else {
                blo_u[0]=lds0[d0+2]; blo_u[1]=lds0[d0+3]; blo_u[2]=lds0[d1+2]; blo_u[3]=lds0[d1+3];
                bhi_u[0]=lds0[d2+2]; bhi_u[1]=lds0[d2+3]; bhi_u[2]=lds0[d3+2]; bhi_u[3]=lds0[d3+3];
            }
            const short8 blo = __builtin_bit_cast(short8, blo_u);
            const short8 bhi = __builtin_bit_cast(short8, bhi_u);

            f32x4 acc = bias4;
            acc = __builtin_amdgcn_mfma_f32_16x16x32_bf16(a_lo, blo, acc, 0, 0, 0);
            acc = __builtin_amdgcn_mfma_f32_16x16x32_bf16(a_hi, bhi, acc, 0, 0, 0);

            // fused-reciprocal LSTM epilogue: 5 exp2 + 2 rcp per pixel
            const float cv = cp[tr4][n];
            const float u  = __builtin_amdgcn_exp2f(acc[0]);
            const float v  = __builtin_amdgcn_exp2f(acc[1]);
            const float wo = __builtin_amdgcn_exp2f(acc[2]);
            const float z  = __builtin_amdgcn_exp2f(acc[3]);
            const float pu = 1.0f + u,  pv = 1.0f + v;
            const float pw = 1.0f + wo, pz = 1.0f + z;
            const float puz = pu * pz;
            const float r1  = __builtin_amdgcn_rcpf(pv * puz);
            const float nc  = fmaf(cv, puz, (1.0f - z) * pv) * r1;
            const float tt2 = __builtin_amdgcn_exp2f(-2.88539008f * nc);
            const float r2  = __builtin_amdgcn_rcpf(pw * (1.0f + tt2));
            nc4[n] = nc;
            nh4[n] = (1.0f - tt2) * r2;
        }

        // dense 16B nontemporal stores (write-once: stream past L2)
        const int rowchan = rowbase0 + tr4*WIDTH;
        f32x4 nhv; nhv[0]=nh4[0]; nhv[1]=nh4[1]; nhv[2]=nh4[2]; nhv[3]=nh4[3];
        f32x4 ncv; ncv[0]=nc4[0]; ncv[1]=nc4[1]; ncv[2]=nc4[2]; ncv[3]=nc4[3];
        __builtin_nontemporal_store(nhv, reinterpret_cast<f32x4*>(out + rowchan));
        __builtin_nontemporal_store(ncv, reinterpret_cast<f32x4*>(out + NC_OFF + rowchan));
    }
}

extern "C" void kernel_launch(void* const* d_in, const int* in_sizes, int n_in,
                              void* d_out, int out_size, void* d_ws, size_t ws_size,
                              hipStream_t stream) {
    (void)in_sizes; (void)n_in; (void)out_size; (void)ws_size;
    const float* x = (const float*)d_in[0];
    const float* h = (const float*)d_in[1];
    const float* c = (const float*)d_in[2];
    const float* W = (const float*)d_in[3];
    const float* b = (const float*)d_in[4];
    float* out = (float*)d_out;

    short* wdst = (short*)d_ws;                                         // 38,912 B
    float* bdst = (float*)((char*)d_ws + WFRAG_SHORTS * sizeof(short)); // +1,216 B

    hipLaunchKernelGGL(wxform_kernel,
                       dim3((WFRAG_SHORTS + BIAS_FLOATS + 255) / 256), dim3(256),
                       0, stream, W, b, wdst, bdst);
    hipLaunchKernelGGL(convlstm_mfma, dim3(BATCH * NG * 128), dim3(256),
                       0, stream, x, h, c, (const short*)wdst, bdst, out);
}